// Round 1
// baseline (374.913 us; speedup 1.0000x reference)
//
#include <hip/hip_runtime.h>

#define N_NODES 50000
#define N_EDGES 800000
#define IN_DIM 128
#define OUT_DIM 64
#define REL_DIM 32
#define NEG_SLOPE 0.01f

// ---- monotonic uint key for float atomic-max (0 == "empty", below all real keys) ----
__device__ __forceinline__ unsigned fkey(float f) {
    unsigned u = __float_as_uint(f);
    return (u & 0x80000000u) ? ~u : (u | 0x80000000u);
}
__device__ __forceinline__ float funkey(unsigned k) {
    unsigned u = (k & 0x80000000u) ? (k & 0x7FFFFFFFu) : ~k;
    return __uint_as_float(u);
}

// K1: z = h @ Wfc^T  [N,64]; s1[n] = Wa[0:64].z[n]; s2[n] = Wa[96:160].z[n]
__global__ __launch_bounds__(256) void k1_fc(const float* __restrict__ h,
                                             const float* __restrict__ Wfc,
                                             const float* __restrict__ Wattn,
                                             float* __restrict__ z,
                                             float* __restrict__ s1,
                                             float* __restrict__ s2) {
    // Wt[k*65 + c] = Wfc[c*128 + k]  (stride 65: conflict-free on write (stride-65 ≡ 1 mod 32)
    // and on read (consecutive lanes))
    __shared__ float Wt[IN_DIM * 65];
    const int t = threadIdx.x;
#pragma unroll
    for (int i = 0; i < 32; ++i) {
        int idx = t + 256 * i;            // 8192 = 64*128 elements
        int c = idx >> 7, k = idx & 127;
        Wt[k * 65 + c] = Wfc[idx];
    }
    __syncthreads();

    const int wave = t >> 6, lane = t & 63;
    const float wa1 = Wattn[lane];
    const float wa2 = Wattn[96 + lane];
    const int gwave = blockIdx.x * 4 + wave;
    const int nwaves = gridDim.x * 4;

    for (int n = gwave; n < N_NODES; n += nwaves) {
        const float* hp = h + (size_t)n * IN_DIM;
        float h0 = hp[lane];
        float h1 = hp[64 + lane];
        float acc = 0.f;
#pragma unroll
        for (int k = 0; k < 64; ++k) {
            float hk = __shfl(h0, k, 64);
            acc += hk * Wt[k * 65 + lane];
        }
#pragma unroll
        for (int k = 0; k < 64; ++k) {
            float hk = __shfl(h1, k, 64);
            acc += hk * Wt[(64 + k) * 65 + lane];
        }
        z[(size_t)n * OUT_DIM + lane] = acc;
        float r1 = acc * wa1, r2 = acc * wa2;
#pragma unroll
        for (int off = 32; off; off >>= 1) {
            r1 += __shfl_xor(r1, off, 64);
            r2 += __shfl_xor(r2, off, 64);
        }
        if (lane == 0) { s1[n] = r1; s2[n] = r2; }
    }
}

// K2: per-edge logit, leaky-relu, segment-max via atomic uint-key max
__global__ __launch_bounds__(256) void k2_logits(const float* __restrict__ p,
                                                 const int* __restrict__ src,
                                                 const int* __restrict__ dst,
                                                 const float* __restrict__ Wattn,
                                                 const float* __restrict__ s1,
                                                 const float* __restrict__ s2,
                                                 float* __restrict__ e_ws,
                                                 unsigned* __restrict__ segmax) {
    __shared__ float wp[REL_DIM];
    if (threadIdx.x < REL_DIM) wp[threadIdx.x] = Wattn[64 + threadIdx.x];
    __syncthreads();
    const int stride = gridDim.x * blockDim.x;
    for (int e = blockIdx.x * blockDim.x + threadIdx.x; e < N_EDGES; e += stride) {
        int s = src[e], d = dst[e];
        const float4* pe = (const float4*)(p + (size_t)e * REL_DIM);
        float dotp = 0.f;
#pragma unroll
        for (int q = 0; q < 8; ++q) {
            float4 v = pe[q];
            dotp += v.x * wp[q * 4 + 0] + v.y * wp[q * 4 + 1]
                  + v.z * wp[q * 4 + 2] + v.w * wp[q * 4 + 3];
        }
        float a = s1[s] + dotp + s2[d];
        float ev = a > 0.f ? a : NEG_SLOPE * a;
        e_ws[e] = ev;
        atomicMax(&segmax[d], fkey(ev));
    }
}

// K3: num = exp(e - segmax[dst]); denom[dst] += num
__global__ __launch_bounds__(256) void k3_num(const int* __restrict__ dst,
                                              const float* __restrict__ e_ws,
                                              const unsigned* __restrict__ segmax,
                                              float* __restrict__ num_ws,
                                              float* __restrict__ denom) {
    const int stride = gridDim.x * blockDim.x;
    for (int e = blockIdx.x * blockDim.x + threadIdx.x; e < N_EDGES; e += stride) {
        int d = dst[e];
        float m = funkey(segmax[d]);
        float num = expf(e_ws[e] - m);
        num_ws[e] = num;
        atomicAdd(&denom[d], num);
    }
}

// K4: wave-per-edge scatter of num * z[src] into out[dst]
__global__ __launch_bounds__(256) void k4_scatter(const int* __restrict__ src,
                                                  const int* __restrict__ dst,
                                                  const float* __restrict__ num_ws,
                                                  const float* __restrict__ z,
                                                  float* __restrict__ out) {
    const int lane = threadIdx.x & 63;
    const int gwave = (blockIdx.x * blockDim.x + threadIdx.x) >> 6;
    const int nwaves = (gridDim.x * blockDim.x) >> 6;
    for (int e = gwave; e < N_EDGES; e += nwaves) {
        int s = src[e], d = dst[e];
        float w = num_ws[e];
        float v = w * z[(size_t)s * OUT_DIM + lane];
        atomicAdd(&out[(size_t)d * OUT_DIM + lane], v);
    }
}

// K5: out[n][c] /= denom[n]  (isolated nodes: denom==0 -> 0)
__global__ __launch_bounds__(256) void k5_norm(float* __restrict__ out,
                                               const float* __restrict__ denom) {
    int i = blockIdx.x * blockDim.x + threadIdx.x;
    if (i < N_NODES * OUT_DIM) {
        float d = denom[i >> 6];
        float v = out[i];
        out[i] = (d != 0.f) ? v / d : 0.f;
    }
}

extern "C" void kernel_launch(void* const* d_in, const int* in_sizes, int n_in,
                              void* d_out, int out_size, void* d_ws, size_t ws_size,
                              hipStream_t stream) {
    const float* h     = (const float*)d_in[0];
    const float* p     = (const float*)d_in[1];
    const int*   src   = (const int*)d_in[2];
    const int*   dst   = (const int*)d_in[3];
    const float* Wfc   = (const float*)d_in[4];
    const float* Wattn = (const float*)d_in[5];
    float* out = (float*)d_out;

    // workspace layout (floats)
    float* ws = (float*)d_ws;
    float*    z      = ws;                       // 3,200,000
    float*    s1     = ws + 3200000;             // 50,000
    float*    s2     = ws + 3250000;             // 50,000
    float*    e_ws   = ws + 3300000;             // 800,000
    float*    num_ws = ws + 4100000;             // 800,000
    unsigned* segmax = (unsigned*)(ws + 4900000);// 50,000
    float*    denom  = ws + 4950000;             // 50,000  (total 20 MB)

    hipMemsetAsync(segmax, 0, N_NODES * sizeof(unsigned), stream);   // 0 < key(-inf)
    hipMemsetAsync(denom, 0, N_NODES * sizeof(float), stream);
    hipMemsetAsync(out, 0, (size_t)N_NODES * OUT_DIM * sizeof(float), stream);

    k1_fc<<<2048, 256, 0, stream>>>(h, Wfc, Wattn, z, s1, s2);
    k2_logits<<<3125, 256, 0, stream>>>(p, src, dst, Wattn, s1, s2, e_ws, segmax);
    k3_num<<<3125, 256, 0, stream>>>(dst, e_ws, segmax, num_ws, denom);
    k4_scatter<<<4096, 256, 0, stream>>>(src, dst, num_ws, z, out);
    k5_norm<<<12500, 256, 0, stream>>>(out, denom);
}

// Round 2
// 329.001 us; speedup vs baseline: 1.1396x; 1.1396x over previous
//
#include <hip/hip_runtime.h>

#define N_NODES 50000
#define N_EDGES 800000
#define IN_DIM 128
#define OUT_DIM 64
#define REL_DIM 32
#define NEG_SLOPE 0.01f

// ---- monotonic uint key for float atomic-max (0 == "empty", below all real keys) ----
__device__ __forceinline__ unsigned fkey(float f) {
    unsigned u = __float_as_uint(f);
    return (u & 0x80000000u) ? ~u : (u | 0x80000000u);
}
__device__ __forceinline__ float funkey(unsigned k) {
    unsigned u = (k & 0x80000000u) ? (k & 0x7FFFFFFFu) : ~k;
    return __uint_as_float(u);
}

// ================= K1: z = h @ Wfc^T (register-tiled), s1/s2 fused =================
// 64 nodes x 64 cols per block, 256 threads, 4x4 micro-tile per thread.
// LDS: W both k-halves [2][64][65] + h half [64][65], stride-65 (odd) => <=2-way conflicts.
__global__ __launch_bounds__(256) void k1_fc(const float* __restrict__ h,
                                             const float* __restrict__ Wfc,
                                             const float* __restrict__ Wattn,
                                             float* __restrict__ z,
                                             float* __restrict__ s1,
                                             float* __restrict__ s2) {
    __shared__ float Wl[2][64][65];   // [half][c][k_local]
    __shared__ float hl[64][65];      // [n_local][k_local]
    const int t = threadIdx.x;

    // stage W (both halves): Wfc is [64][128] row-major; 2048 float4, 8 per thread
    {
        const float4* W4 = (const float4*)Wfc;
#pragma unroll
        for (int i = 0; i < 8; ++i) {
            int idx = t + 256 * i;        // 0..2047
            int c = idx >> 5;             // 32 float4 per row
            int k4 = idx & 31;
            float4 v = W4[idx];
            int Hh = k4 >> 4;
            int lk = (k4 & 15) * 4;
            Wl[Hh][c][lk]   = v.x;
            Wl[Hh][c][lk+1] = v.y;
            Wl[Hh][c][lk+2] = v.z;
            Wl[Hh][c][lk+3] = v.w;
        }
    }

    const int cg = t & 15, ng = t >> 4;   // 16 col-groups x 16 node-groups
    const int c0 = cg * 4;
    float wa1[4], wa2[4];
#pragma unroll
    for (int j = 0; j < 4; ++j) { wa1[j] = Wattn[c0 + j]; wa2[j] = Wattn[96 + c0 + j]; }

    const int n0 = blockIdx.x * 64;
    float acc[4][4] = {};

#pragma unroll
    for (int H = 0; H < 2; ++H) {
        __syncthreads();                  // protect hl from previous half's readers (and cover W stage)
        const float4* h4 = (const float4*)h;
#pragma unroll
        for (int i = 0; i < 4; ++i) {     // 1024 float4, 4 per thread
            int idx = t + 256 * i;
            int n = idx >> 4;
            int k4 = idx & 15;
            int gn = n0 + n; if (gn > N_NODES - 1) gn = N_NODES - 1;
            float4 v = h4[(size_t)gn * 32 + H * 16 + k4];
            hl[n][k4*4]   = v.x;
            hl[n][k4*4+1] = v.y;
            hl[n][k4*4+2] = v.z;
            hl[n][k4*4+3] = v.w;
        }
        __syncthreads();
#pragma unroll 4
        for (int k = 0; k < 64; ++k) {
            float wv[4], hv[4];
#pragma unroll
            for (int j = 0; j < 4; ++j) wv[j] = Wl[H][c0 + j][k];
#pragma unroll
            for (int i = 0; i < 4; ++i) hv[i] = hl[ng*4 + i][k];
#pragma unroll
            for (int i = 0; i < 4; ++i)
#pragma unroll
                for (int j = 0; j < 4; ++j) acc[i][j] += hv[i] * wv[j];
        }
    }

    // epilogue: z stores (float4) + fused s1/s2 (reduce across the 16 col-groups = 16-lane groups)
#pragma unroll
    for (int i = 0; i < 4; ++i) {
        int gn = n0 + ng * 4 + i;
        float4 st; st.x = acc[i][0]; st.y = acc[i][1]; st.z = acc[i][2]; st.w = acc[i][3];
        float r1 = acc[i][0]*wa1[0] + acc[i][1]*wa1[1] + acc[i][2]*wa1[2] + acc[i][3]*wa1[3];
        float r2 = acc[i][0]*wa2[0] + acc[i][1]*wa2[1] + acc[i][2]*wa2[2] + acc[i][3]*wa2[3];
#pragma unroll
        for (int off = 1; off < 16; off <<= 1) {
            r1 += __shfl_xor(r1, off, 64);
            r2 += __shfl_xor(r2, off, 64);
        }
        if (gn < N_NODES) {
            ((float4*)z)[(size_t)gn * 16 + cg] = st;
            if (cg == 0) { s1[gn] = r1; s2[gn] = r2; }
        }
    }
}

// ================= K2: per-edge logit + leaky-relu + segment-max + dst histogram =================
__global__ __launch_bounds__(256) void k2_logits(const float* __restrict__ p,
                                                 const int* __restrict__ src,
                                                 const int* __restrict__ dst,
                                                 const float* __restrict__ Wattn,
                                                 const float* __restrict__ s1,
                                                 const float* __restrict__ s2,
                                                 float* __restrict__ e_ws,
                                                 unsigned* __restrict__ segmax,
                                                 unsigned* __restrict__ count) {
    __shared__ float wp[REL_DIM];
    if (threadIdx.x < REL_DIM) wp[threadIdx.x] = Wattn[64 + threadIdx.x];
    __syncthreads();
    const int stride = gridDim.x * blockDim.x;
    for (int e = blockIdx.x * blockDim.x + threadIdx.x; e < N_EDGES; e += stride) {
        int s = src[e], d = dst[e];
        const float4* pe = (const float4*)(p + (size_t)e * REL_DIM);
        float dotp = 0.f;
#pragma unroll
        for (int q = 0; q < 8; ++q) {
            float4 v = pe[q];
            dotp += v.x * wp[q*4+0] + v.y * wp[q*4+1] + v.z * wp[q*4+2] + v.w * wp[q*4+3];
        }
        float a = s1[s] + dotp + s2[d];
        float ev = a > 0.f ? a : NEG_SLOPE * a;
        e_ws[e] = ev;
        atomicMax(&segmax[d], fkey(ev));
        atomicAdd(&count[d], 1u);
    }
}

// ================= K2b: exclusive scan of count -> offs, cursor (single block) =================
__global__ __launch_bounds__(1024) void k2b_scan(const unsigned* __restrict__ count,
                                                 unsigned* __restrict__ offs,
                                                 unsigned* __restrict__ cursor) {
    __shared__ unsigned part[1024];
    const int t = threadIdx.x;
    const int CH = 49;                       // 1024*49 >= 50000
    int lo = t * CH, hi = lo + CH; if (hi > N_NODES) hi = N_NODES;
    unsigned s = 0;
    for (int i = lo; i < hi; ++i) s += count[i];
    part[t] = s;
    __syncthreads();
    for (int off = 1; off < 1024; off <<= 1) {
        unsigned v = (t >= off) ? part[t - off] : 0u;
        __syncthreads();
        part[t] += v;
        __syncthreads();
    }
    unsigned run = part[t] - s;              // exclusive prefix
    for (int i = lo; i < hi; ++i) {
        offs[i] = run; cursor[i] = run;
        run += count[i];
    }
    if (t == 1023) offs[N_NODES] = part[1023];
}

// ================= K3: permute (e_logit, src) into dst-grouped order =================
__global__ __launch_bounds__(256) void k3_permute(const int* __restrict__ src,
                                                  const int* __restrict__ dst,
                                                  const float* __restrict__ e_ws,
                                                  unsigned* __restrict__ cursor,
                                                  float2* __restrict__ pair) {
    const int stride = gridDim.x * blockDim.x;
    for (int e = blockIdx.x * blockDim.x + threadIdx.x; e < N_EDGES; e += stride) {
        int d = dst[e];
        unsigned pos = atomicAdd(&cursor[d], 1u);
        pair[pos] = make_float2(e_ws[e], __int_as_float(src[e]));
    }
}

// ================= K4: wave-per-node segment aggregate (softmax + weighted sum + normalize) =================
__global__ __launch_bounds__(256) void k4_agg(const unsigned* __restrict__ offs,
                                              const unsigned* __restrict__ segmax,
                                              const float2* __restrict__ pair,
                                              const float* __restrict__ z,
                                              float* __restrict__ out) {
    const int lane = threadIdx.x & 63;
    const int wid = (blockIdx.x * blockDim.x + threadIdx.x) >> 6;
    const int nw = (gridDim.x * blockDim.x) >> 6;
    for (int n = wid; n < N_NODES; n += nw) {
        float m = funkey(segmax[n]);
        int lo = offs[n], hi = offs[n + 1];
        float acc = 0.f, den = 0.f;
        int i = lo;
        if (i < hi) {
            float2 pr = pair[i];
            while (i + 1 < hi) {
                float2 nx = pair[i + 1];           // prefetch next edge's scalars
                float num = __expf(pr.x - m);
                int s = __float_as_int(pr.y);
                acc += num * z[(size_t)s * OUT_DIM + lane];
                den += num;
                pr = nx; ++i;
            }
            float num = __expf(pr.x - m);
            int s = __float_as_int(pr.y);
            acc += num * z[(size_t)s * OUT_DIM + lane];
            den += num;
        }
        out[(size_t)n * OUT_DIM + lane] = (hi > lo) ? acc / den : 0.f;
    }
}

extern "C" void kernel_launch(void* const* d_in, const int* in_sizes, int n_in,
                              void* d_out, int out_size, void* d_ws, size_t ws_size,
                              hipStream_t stream) {
    const float* h     = (const float*)d_in[0];
    const float* p     = (const float*)d_in[1];
    const int*   src   = (const int*)d_in[2];
    const int*   dst   = (const int*)d_in[3];
    const float* Wfc   = (const float*)d_in[4];
    const float* Wattn = (const float*)d_in[5];
    float* out = (float*)d_out;

    // workspace layout (float words)
    float* ws = (float*)d_ws;
    float*    z      = ws;                        // 3,200,000
    float*    s1     = ws + 3200000;              // 50,000
    float*    s2     = ws + 3250000;              // 50,000
    float*    e_ws   = ws + 3300000;              // 800,000
    unsigned* segmax = (unsigned*)(ws + 4100000); // 50,000
    unsigned* count  = (unsigned*)(ws + 4150000); // 50,000
    unsigned* offs   = (unsigned*)(ws + 4200000); // 50,001
    unsigned* cursor = (unsigned*)(ws + 4250016); // 50,000
    float2*   pair   = (float2*)(ws + 4300032);   // 800,000 float2 (16B-aligned base)
    // total: 5,900,032 floats = 23.6 MB

    hipMemsetAsync(segmax, 0, N_NODES * sizeof(unsigned), stream);  // 0 < key of any float
    hipMemsetAsync(count,  0, N_NODES * sizeof(unsigned), stream);

    k1_fc<<<(N_NODES + 63) / 64, 256, 0, stream>>>(h, Wfc, Wattn, z, s1, s2);
    k2_logits<<<3125, 256, 0, stream>>>(p, src, dst, Wattn, s1, s2, e_ws, segmax, count);
    k2b_scan<<<1, 1024, 0, stream>>>(count, offs, cursor);
    k3_permute<<<3125, 256, 0, stream>>>(src, dst, e_ws, cursor, pair);
    k4_agg<<<2048, 256, 0, stream>>>(offs, segmax, pair, z, out);
}

// Round 3
// 205.124 us; speedup vs baseline: 1.8277x; 1.6039x over previous
//
#include <hip/hip_runtime.h>

#define N_NODES 50000
#define N_EDGES 800000
#define IN_DIM 128
#define OUT_DIM 64
#define REL_DIM 32
#define NEG_SLOPE 0.01f
#define SCAN_BLOCKS 196   // ceil(50000/256)

// ---- monotonic uint key for float atomic-max (0 == "empty", below all real keys) ----
__device__ __forceinline__ unsigned fkey(float f) {
    unsigned u = __float_as_uint(f);
    return (u & 0x80000000u) ? ~u : (u | 0x80000000u);
}
__device__ __forceinline__ float funkey(unsigned k) {
    unsigned u = (k & 0x80000000u) ? (k & 0x7FFFFFFFu) : ~k;
    return __uint_as_float(u);
}

// ================= K1: z = h @ Wfc^T (register-tiled), s1/s2 fused =================
__global__ __launch_bounds__(256) void k1_fc(const float* __restrict__ h,
                                             const float* __restrict__ Wfc,
                                             const float* __restrict__ Wattn,
                                             float* __restrict__ z,
                                             float* __restrict__ s1,
                                             float* __restrict__ s2) {
    __shared__ float Wl[2][64][65];
    __shared__ float hl[64][65];
    const int t = threadIdx.x;
    {
        const float4* W4 = (const float4*)Wfc;
#pragma unroll
        for (int i = 0; i < 8; ++i) {
            int idx = t + 256 * i;
            int c = idx >> 5;
            int k4 = idx & 31;
            float4 v = W4[idx];
            int Hh = k4 >> 4;
            int lk = (k4 & 15) * 4;
            Wl[Hh][c][lk]   = v.x;
            Wl[Hh][c][lk+1] = v.y;
            Wl[Hh][c][lk+2] = v.z;
            Wl[Hh][c][lk+3] = v.w;
        }
    }
    const int cg = t & 15, ng = t >> 4;
    const int c0 = cg * 4;
    float wa1[4], wa2[4];
#pragma unroll
    for (int j = 0; j < 4; ++j) { wa1[j] = Wattn[c0 + j]; wa2[j] = Wattn[96 + c0 + j]; }

    const int n0 = blockIdx.x * 64;
    float acc[4][4] = {};

#pragma unroll
    for (int H = 0; H < 2; ++H) {
        __syncthreads();
        const float4* h4 = (const float4*)h;
#pragma unroll
        for (int i = 0; i < 4; ++i) {
            int idx = t + 256 * i;
            int n = idx >> 4;
            int k4 = idx & 15;
            int gn = n0 + n; if (gn > N_NODES - 1) gn = N_NODES - 1;
            float4 v = h4[(size_t)gn * 32 + H * 16 + k4];
            hl[n][k4*4]   = v.x;
            hl[n][k4*4+1] = v.y;
            hl[n][k4*4+2] = v.z;
            hl[n][k4*4+3] = v.w;
        }
        __syncthreads();
#pragma unroll 4
        for (int k = 0; k < 64; ++k) {
            float wv[4], hv[4];
#pragma unroll
            for (int j = 0; j < 4; ++j) wv[j] = Wl[H][c0 + j][k];
#pragma unroll
            for (int i = 0; i < 4; ++i) hv[i] = hl[ng*4 + i][k];
#pragma unroll
            for (int i = 0; i < 4; ++i)
#pragma unroll
                for (int j = 0; j < 4; ++j) acc[i][j] += hv[i] * wv[j];
        }
    }
#pragma unroll
    for (int i = 0; i < 4; ++i) {
        int gn = n0 + ng * 4 + i;
        float4 st; st.x = acc[i][0]; st.y = acc[i][1]; st.z = acc[i][2]; st.w = acc[i][3];
        float r1 = acc[i][0]*wa1[0] + acc[i][1]*wa1[1] + acc[i][2]*wa1[2] + acc[i][3]*wa1[3];
        float r2 = acc[i][0]*wa2[0] + acc[i][1]*wa2[1] + acc[i][2]*wa2[2] + acc[i][3]*wa2[3];
#pragma unroll
        for (int off = 1; off < 16; off <<= 1) {
            r1 += __shfl_xor(r1, off, 64);
            r2 += __shfl_xor(r2, off, 64);
        }
        if (gn < N_NODES) {
            ((float4*)z)[(size_t)gn * 16 + cg] = st;
            if (cg == 0) { s1[gn] = r1; s2[gn] = r2; }
        }
    }
}

// ================= K2: dst histogram only =================
__global__ __launch_bounds__(256) void k2_count(const int* __restrict__ dst,
                                                unsigned* __restrict__ count) {
    const int stride = gridDim.x * blockDim.x;
    for (int e = blockIdx.x * blockDim.x + threadIdx.x; e < N_EDGES; e += stride)
        atomicAdd(&count[dst[e]], 1u);
}

// ================= hierarchical exclusive scan: A (per-block), B (block sums), C (add back) ====
__global__ __launch_bounds__(256) void scanA(const unsigned* __restrict__ count,
                                             unsigned* __restrict__ offs,
                                             unsigned* __restrict__ bsum) {
    __shared__ unsigned sd[256];
    const int t = threadIdx.x;
    const int idx = blockIdx.x * 256 + t;
    unsigned v = (idx < N_NODES) ? count[idx] : 0u;
    sd[t] = v;
    __syncthreads();
#pragma unroll
    for (int off = 1; off < 256; off <<= 1) {
        unsigned tmp = (t >= off) ? sd[t - off] : 0u;
        __syncthreads();
        sd[t] += tmp;
        __syncthreads();
    }
    if (idx < N_NODES) offs[idx] = sd[t] - v;      // exclusive, block-local
    if (t == 255) bsum[blockIdx.x] = sd[255];
}

__global__ __launch_bounds__(256) void scanB(unsigned* __restrict__ bsum,
                                             unsigned* __restrict__ boff,
                                             unsigned* __restrict__ offs) {
    __shared__ unsigned sd[256];
    const int t = threadIdx.x;
    unsigned v = (t < SCAN_BLOCKS) ? bsum[t] : 0u;
    sd[t] = v;
    __syncthreads();
#pragma unroll
    for (int off = 1; off < 256; off <<= 1) {
        unsigned tmp = (t >= off) ? sd[t - off] : 0u;
        __syncthreads();
        sd[t] += tmp;
        __syncthreads();
    }
    if (t < SCAN_BLOCKS) boff[t] = sd[t] - v;      // exclusive
    if (t == 0) offs[N_NODES] = N_EDGES;
}

__global__ __launch_bounds__(256) void scanC(unsigned* __restrict__ offs,
                                             const unsigned* __restrict__ boff,
                                             unsigned* __restrict__ cursor) {
    const int idx = blockIdx.x * 256 + threadIdx.x;
    if (idx < N_NODES) {
        unsigned o = offs[idx] + boff[blockIdx.x];
        offs[idx] = o;
        cursor[idx] = o;
    }
}

// ================= K3: fused logits + leaky-relu + segmax + permute into dst order =============
__global__ __launch_bounds__(256) void k3_fused(const float* __restrict__ p,
                                                const int* __restrict__ src,
                                                const int* __restrict__ dst,
                                                const float* __restrict__ Wattn,
                                                const float* __restrict__ s1,
                                                const float* __restrict__ s2,
                                                unsigned* __restrict__ cursor,
                                                unsigned* __restrict__ segmax,
                                                float2* __restrict__ pair) {
    __shared__ float wp[REL_DIM];
    if (threadIdx.x < REL_DIM) wp[threadIdx.x] = Wattn[64 + threadIdx.x];
    __syncthreads();
    const int stride = gridDim.x * blockDim.x;
    for (int e = blockIdx.x * blockDim.x + threadIdx.x; e < N_EDGES; e += stride) {
        int s = src[e], d = dst[e];
        const float4* pe = (const float4*)(p + (size_t)e * REL_DIM);
        float dotp = 0.f;
#pragma unroll
        for (int q = 0; q < 8; ++q) {
            float4 v = pe[q];
            dotp += v.x * wp[q*4+0] + v.y * wp[q*4+1] + v.z * wp[q*4+2] + v.w * wp[q*4+3];
        }
        float a = s1[s] + dotp + s2[d];
        float ev = a > 0.f ? a : NEG_SLOPE * a;
        atomicMax(&segmax[d], fkey(ev));
        unsigned pos = atomicAdd(&cursor[d], 1u);
        pair[pos] = make_float2(ev, __int_as_float(s));
    }
}

// ================= K4: wave-per-node segment aggregate, 2-edge unrolled ========================
__global__ __launch_bounds__(256) void k4_agg(const unsigned* __restrict__ offs,
                                              const unsigned* __restrict__ segmax,
                                              const float2* __restrict__ pair,
                                              const float* __restrict__ z,
                                              float* __restrict__ out) {
    const int lane = threadIdx.x & 63;
    const int wid = (blockIdx.x * blockDim.x + threadIdx.x) >> 6;
    const int nw = (gridDim.x * blockDim.x) >> 6;
    for (int n = wid; n < N_NODES; n += nw) {
        float m = funkey(segmax[n]);
        int lo = offs[n], hi = offs[n + 1];
        float acc = 0.f, den = 0.f;
        int i = lo;
        for (; i + 1 < hi; i += 2) {
            float2 p0 = pair[i];
            float2 p1 = pair[i + 1];
            int s0 = __float_as_int(p0.y);
            int s1i = __float_as_int(p1.y);
            float z0 = z[(size_t)s0 * OUT_DIM + lane];
            float z1 = z[(size_t)s1i * OUT_DIM + lane];
            float n0 = __expf(p0.x - m);
            float n1 = __expf(p1.x - m);
            acc += n0 * z0 + n1 * z1;
            den += n0 + n1;
        }
        if (i < hi) {
            float2 p0 = pair[i];
            int s0 = __float_as_int(p0.y);
            float n0 = __expf(p0.x - m);
            acc += n0 * z[(size_t)s0 * OUT_DIM + lane];
            den += n0;
        }
        out[(size_t)n * OUT_DIM + lane] = (hi > lo) ? acc / den : 0.f;
    }
}

extern "C" void kernel_launch(void* const* d_in, const int* in_sizes, int n_in,
                              void* d_out, int out_size, void* d_ws, size_t ws_size,
                              hipStream_t stream) {
    const float* h     = (const float*)d_in[0];
    const float* p     = (const float*)d_in[1];
    const int*   src   = (const int*)d_in[2];
    const int*   dst   = (const int*)d_in[3];
    const float* Wfc   = (const float*)d_in[4];
    const float* Wattn = (const float*)d_in[5];
    float* out = (float*)d_out;

    // workspace layout (float words)
    float* ws = (float*)d_ws;
    float*    z      = ws;                         // 3,200,000
    float*    s1     = ws + 3200000;               // 50,000
    float*    s2     = ws + 3250000;               // 50,000
    unsigned* segmax = (unsigned*)(ws + 3300000);  // 50,000 \ contiguous: one memset
    unsigned* count  = (unsigned*)(ws + 3350000);  // 50,000 /
    unsigned* offs   = (unsigned*)(ws + 3400000);  // 50,001
    unsigned* cursor = (unsigned*)(ws + 3450016);  // 50,000
    unsigned* bsum   = (unsigned*)(ws + 3500016);  // 256
    unsigned* boff   = (unsigned*)(ws + 3500272);  // 256
    float2*   pair   = (float2*)(ws + 3500528);    // 800,000 float2 (16B-aligned: 3500528%4==0)
    // total: 5,100,528 floats = 20.4 MB

    hipMemsetAsync(segmax, 0, 2 * N_NODES * sizeof(unsigned), stream);  // segmax+count

    k1_fc<<<(N_NODES + 63) / 64, 256, 0, stream>>>(h, Wfc, Wattn, z, s1, s2);
    k2_count<<<1024, 256, 0, stream>>>(dst, count);
    scanA<<<SCAN_BLOCKS, 256, 0, stream>>>(count, offs, bsum);
    scanB<<<1, 256, 0, stream>>>(bsum, boff, offs);
    scanC<<<SCAN_BLOCKS, 256, 0, stream>>>(offs, boff, cursor);
    k3_fused<<<3125, 256, 0, stream>>>(p, src, dst, Wattn, s1, s2, cursor, segmax, pair);
    k4_agg<<<2048, 256, 0, stream>>>(offs, segmax, pair, z, out);
}

// Round 4
// 164.472 us; speedup vs baseline: 2.2795x; 1.2472x over previous
//
#include <hip/hip_runtime.h>
#include <hip/hip_bf16.h>

#define N_NODES 50000
#define N_EDGES 800000
#define IN_DIM 128
#define OUT_DIM 64
#define REL_DIM 32
#define NEG_SLOPE 0.01f
#define SCAN_BLOCKS 196   // ceil(50000/256)

// ================= K1: z = h @ Wfc^T (register-tiled, b128 LDS reads), s1/s2 fused ============
// 64 nodes x 64 cols per block, 256 threads, 4x4 micro-tile.
// LDS k-major [k][68]: rows 272B (16B-aligned), bank-shift 4/row; staged writes are
// 64-consecutive-float per wave (conflict-free), inner reads are float4 broadcast x16 (free).
// z output stored as bf16 (halves k4 gather traffic); s1/s2 stay fp32 (logit precision).
__global__ __launch_bounds__(256) void k1_fc(const float* __restrict__ h,
                                             const float* __restrict__ Wfc,
                                             const float* __restrict__ Wattn,
                                             __hip_bfloat16* __restrict__ zb,
                                             float* __restrict__ s1,
                                             float* __restrict__ s2) {
    __shared__ float Wl[64][68];   // [k_local][c]
    __shared__ float hl[64][68];   // [k_local][n]
    const int t = threadIdx.x;
    const int cg = t & 15, ng = t >> 4;
    const int c0 = cg * 4;
    float wa1[4], wa2[4];
#pragma unroll
    for (int j = 0; j < 4; ++j) { wa1[j] = Wattn[c0 + j]; wa2[j] = Wattn[96 + c0 + j]; }

    const int n0 = blockIdx.x * 64;
    float acc[4][4] = {};
    const float4* W4 = (const float4*)Wfc;   // [64][32] float4
    const float4* h4 = (const float4*)h;     // [N][32] float4

#pragma unroll
    for (int H = 0; H < 2; ++H) {
        __syncthreads();   // protect LDS from previous half's readers
#pragma unroll
        for (int i = 0; i < 4; ++i) {
            int idx = t + 256 * i;           // 0..1023
            int c = idx & 63, k4 = idx >> 6; // wave: 64 consecutive c, same k4
            float4 v = W4[c * 32 + H * 16 + k4];
            Wl[4*k4+0][c] = v.x; Wl[4*k4+1][c] = v.y;
            Wl[4*k4+2][c] = v.z; Wl[4*k4+3][c] = v.w;
        }
#pragma unroll
        for (int i = 0; i < 4; ++i) {
            int idx = t + 256 * i;
            int n = idx & 63, k4 = idx >> 6;
            int gn = n0 + n; if (gn > N_NODES - 1) gn = N_NODES - 1;
            float4 v = h4[(size_t)gn * 32 + H * 16 + k4];
            hl[4*k4+0][n] = v.x; hl[4*k4+1][n] = v.y;
            hl[4*k4+2][n] = v.z; hl[4*k4+3][n] = v.w;
        }
        __syncthreads();
#pragma unroll 8
        for (int k = 0; k < 64; ++k) {
            float4 wv = *(const float4*)&Wl[k][c0];
            float4 hv = *(const float4*)&hl[k][ng * 4];
            float wvf[4] = {wv.x, wv.y, wv.z, wv.w};
            float hvf[4] = {hv.x, hv.y, hv.z, hv.w};
#pragma unroll
            for (int i = 0; i < 4; ++i)
#pragma unroll
                for (int j = 0; j < 4; ++j) acc[i][j] += hvf[i] * wvf[j];
        }
    }

#pragma unroll
    for (int i = 0; i < 4; ++i) {
        int gn = n0 + ng * 4 + i;
        float r1 = acc[i][0]*wa1[0] + acc[i][1]*wa1[1] + acc[i][2]*wa1[2] + acc[i][3]*wa1[3];
        float r2 = acc[i][0]*wa2[0] + acc[i][1]*wa2[1] + acc[i][2]*wa2[2] + acc[i][3]*wa2[3];
#pragma unroll
        for (int off = 1; off < 16; off <<= 1) {
            r1 += __shfl_xor(r1, off, 64);
            r2 += __shfl_xor(r2, off, 64);
        }
        if (gn < N_NODES) {
            __hip_bfloat16 b0 = __float2bfloat16(acc[i][0]);
            __hip_bfloat16 b1 = __float2bfloat16(acc[i][1]);
            __hip_bfloat16 b2 = __float2bfloat16(acc[i][2]);
            __hip_bfloat16 b3 = __float2bfloat16(acc[i][3]);
            ushort4 st;
            st.x = *(unsigned short*)&b0; st.y = *(unsigned short*)&b1;
            st.z = *(unsigned short*)&b2; st.w = *(unsigned short*)&b3;
            ((ushort4*)zb)[(size_t)gn * 16 + cg] = st;
            if (cg == 0) { s1[gn] = r1; s2[gn] = r2; }
        }
    }
}

// ================= K2: dst histogram =================
__global__ __launch_bounds__(256) void k2_count(const int* __restrict__ dst,
                                                unsigned* __restrict__ count) {
    const int stride = gridDim.x * blockDim.x;
    for (int e = blockIdx.x * blockDim.x + threadIdx.x; e < N_EDGES; e += stride)
        atomicAdd(&count[dst[e]], 1u);
}

// ================= hierarchical exclusive scan =================
__global__ __launch_bounds__(256) void scanA(const unsigned* __restrict__ count,
                                             unsigned* __restrict__ offs,
                                             unsigned* __restrict__ bsum) {
    __shared__ unsigned sd[256];
    const int t = threadIdx.x;
    const int idx = blockIdx.x * 256 + t;
    unsigned v = (idx < N_NODES) ? count[idx] : 0u;
    sd[t] = v;
    __syncthreads();
#pragma unroll
    for (int off = 1; off < 256; off <<= 1) {
        unsigned tmp = (t >= off) ? sd[t - off] : 0u;
        __syncthreads();
        sd[t] += tmp;
        __syncthreads();
    }
    if (idx < N_NODES) offs[idx] = sd[t] - v;
    if (t == 255) bsum[blockIdx.x] = sd[255];
}

__global__ __launch_bounds__(256) void scanB(unsigned* __restrict__ bsum,
                                             unsigned* __restrict__ boff,
                                             unsigned* __restrict__ offs) {
    __shared__ unsigned sd[256];
    const int t = threadIdx.x;
    unsigned v = (t < SCAN_BLOCKS) ? bsum[t] : 0u;
    sd[t] = v;
    __syncthreads();
#pragma unroll
    for (int off = 1; off < 256; off <<= 1) {
        unsigned tmp = (t >= off) ? sd[t - off] : 0u;
        __syncthreads();
        sd[t] += tmp;
        __syncthreads();
    }
    if (t < SCAN_BLOCKS) boff[t] = sd[t] - v;
    if (t == 0) offs[N_NODES] = N_EDGES;
}

__global__ __launch_bounds__(256) void scanC(unsigned* __restrict__ offs,
                                             const unsigned* __restrict__ boff,
                                             unsigned* __restrict__ cursor) {
    const int idx = blockIdx.x * 256 + threadIdx.x;
    if (idx < N_NODES) {
        unsigned o = offs[idx] + boff[blockIdx.x];
        offs[idx] = o;
        cursor[idx] = o;
    }
}

// ================= K3: fused logits + leaky-relu + permute into dst order (max-free) ==========
__global__ __launch_bounds__(256) void k3_fused(const float* __restrict__ p,
                                                const int* __restrict__ src,
                                                const int* __restrict__ dst,
                                                const float* __restrict__ Wattn,
                                                const float* __restrict__ s1,
                                                const float* __restrict__ s2,
                                                unsigned* __restrict__ cursor,
                                                float2* __restrict__ pair) {
    __shared__ float wp[REL_DIM];
    if (threadIdx.x < REL_DIM) wp[threadIdx.x] = Wattn[64 + threadIdx.x];
    __syncthreads();
    const int stride = gridDim.x * blockDim.x;
    for (int e = blockIdx.x * blockDim.x + threadIdx.x; e < N_EDGES; e += stride) {
        int s = src[e], d = dst[e];
        const float4* pe = (const float4*)(p + (size_t)e * REL_DIM);
        float dotp = 0.f;
#pragma unroll
        for (int q = 0; q < 8; ++q) {
            float4 v = pe[q];
            dotp += v.x * wp[q*4+0] + v.y * wp[q*4+1] + v.z * wp[q*4+2] + v.w * wp[q*4+3];
        }
        float a = s1[s] + dotp + s2[d];
        float ev = a > 0.f ? a : NEG_SLOPE * a;
        unsigned pos = atomicAdd(&cursor[d], 1u);
        pair[pos] = make_float2(ev, __int_as_float(s));
    }
}

// ================= K4: wave-per-node segment aggregate (max-free softmax, bf16 z) =============
__global__ __launch_bounds__(256) void k4_agg(const unsigned* __restrict__ offs,
                                              const float2* __restrict__ pair,
                                              const __hip_bfloat16* __restrict__ zb,
                                              float* __restrict__ out) {
    const int lane = threadIdx.x & 63;
    const int wid = (blockIdx.x * blockDim.x + threadIdx.x) >> 6;
    const int nw = (gridDim.x * blockDim.x) >> 6;
    for (int n = wid; n < N_NODES; n += nw) {
        int lo = offs[n], hi = offs[n + 1];
        float acc = 0.f, den = 0.f;
        int i = lo;
        for (; i + 1 < hi; i += 2) {
            float2 p0 = pair[i];
            float2 p1 = pair[i + 1];
            int s0 = __float_as_int(p0.y);
            int s1i = __float_as_int(p1.y);
            float z0 = __bfloat162float(zb[(size_t)s0 * OUT_DIM + lane]);
            float z1 = __bfloat162float(zb[(size_t)s1i * OUT_DIM + lane]);
            float n0 = __expf(p0.x);
            float n1 = __expf(p1.x);
            acc += n0 * z0 + n1 * z1;
            den += n0 + n1;
        }
        if (i < hi) {
            float2 p0 = pair[i];
            int s0 = __float_as_int(p0.y);
            float n0 = __expf(p0.x);
            acc += n0 * __bfloat162float(zb[(size_t)s0 * OUT_DIM + lane]);
            den += n0;
        }
        out[(size_t)n * OUT_DIM + lane] = (hi > lo) ? acc / den : 0.f;
    }
}

extern "C" void kernel_launch(void* const* d_in, const int* in_sizes, int n_in,
                              void* d_out, int out_size, void* d_ws, size_t ws_size,
                              hipStream_t stream) {
    const float* h     = (const float*)d_in[0];
    const float* p     = (const float*)d_in[1];
    const int*   src   = (const int*)d_in[2];
    const int*   dst   = (const int*)d_in[3];
    const float* Wfc   = (const float*)d_in[4];
    const float* Wattn = (const float*)d_in[5];
    float* out = (float*)d_out;

    // workspace layout (float words)
    float* ws = (float*)d_ws;
    __hip_bfloat16* zb = (__hip_bfloat16*)ws;      // 3,200,000 bf16 = 1,600,000 floats
    float*    s1     = ws + 1600000;               // 50,000
    float*    s2     = ws + 1650000;               // 50,000
    unsigned* count  = (unsigned*)(ws + 1700000);  // 50,000
    unsigned* offs   = (unsigned*)(ws + 1750000);  // 50,001
    unsigned* cursor = (unsigned*)(ws + 1800016);  // 50,000
    unsigned* bsum   = (unsigned*)(ws + 1850016);  // 256
    unsigned* boff   = (unsigned*)(ws + 1850272);  // 256
    float2*   pair   = (float2*)(ws + 1850528);    // 800,000 float2 (16B-aligned)
    // total: 3,450,528 floats = 13.8 MB

    hipMemsetAsync(count, 0, N_NODES * sizeof(unsigned), stream);

    k1_fc<<<(N_NODES + 63) / 64, 256, 0, stream>>>(h, Wfc, Wattn, zb, s1, s2);
    k2_count<<<1024, 256, 0, stream>>>(dst, count);
    scanA<<<SCAN_BLOCKS, 256, 0, stream>>>(count, offs, bsum);
    scanB<<<1, 256, 0, stream>>>(bsum, boff, offs);
    scanC<<<SCAN_BLOCKS, 256, 0, stream>>>(offs, boff, cursor);
    k3_fused<<<3125, 256, 0, stream>>>(p, src, dst, Wattn, s1, s2, cursor, pair);
    k4_agg<<<2048, 256, 0, stream>>>(offs, pair, zb, out);
}